// Round 16
// baseline (2098.928 us; speedup 1.0000x reference)
//
#include <hip/hip_runtime.h>
#include <hip/hip_bf16.h>
#include <math.h>

constexpr int NV = 32000, ND = 1024, NH = 16, NHD = 64, NL = 3, NDFF = 4096;
constexpr int NE = 8, NB = 2, NS = 1024, NT = NB * NS;
constexpr int ECAP = 1280;   // per-expert compact-row capacity (expected ~512)

typedef __attribute__((ext_vector_type(8))) short bf16x8;
typedef __attribute__((ext_vector_type(8))) _Float16 f16x8;
typedef __attribute__((ext_vector_type(4))) float f32x4;
typedef __hip_bfloat16 bf16;

__device__ __forceinline__ bf16 f2b(float v) { return __float2bfloat16(v); }

// Async 16B global->LDS (proven bit-identical to reg-staged path, rounds 2-4)
__device__ __forceinline__ void async16(char* lds, const void* g) {
    __builtin_amdgcn_global_load_lds((const __attribute__((address_space(1))) void*)g,
                                     (__attribute__((address_space(3))) void*)lds,
                                     16, 0, 0);
}

// ---------------------------------------------------------------------------
__global__ void yarn_kernel(float* __restrict__ c, float* __restrict__ sn) {
    int idx = blockIdx.x * blockDim.x + threadIdx.x;   // NS*32 threads
    int j = idx & 31;
    int s = idx >> 5;
    double ex = (double)(2 * j) / 64.0;
    double fe = 1.0 / pow(10000.0, ex);
    double fi = fe / 8.0;
    double lin = ((double)j - 8.0) / 13.0;
    double mask = 1.0 - fmin(fmax(lin, 0.0), 1.0);
    double invf = fi * (1.0 - mask) + fe * mask;
    double ms = 0.1 * log(8.0) + 1.0;
    double fr = (double)s * invf;
    c[idx]  = (float)(cos(fr) * ms);
    sn[idx] = (float)(sin(fr) * ms);
}

// ---------------------------------------------------------------------------
__global__ void embed_kernel(const int* __restrict__ src, const float* __restrict__ emb,
                             float* __restrict__ x,
                             _Float16* __restrict__ xh, _Float16* __restrict__ xl) {
    int idx = blockIdx.x * blockDim.x + threadIdx.x;   // NT*ND threads
    int t = idx >> 10;
    int d = idx & 1023;
    int s = src[t];
    s = s < 0 ? 0 : (s > NV - 1 ? NV - 1 : s);
    float v = emb[(size_t)s * ND + d] * 32.0f;
    x[idx] = v;
    _Float16 h = (_Float16)v;
    xh[idx] = h;
    xl[idx] = (_Float16)(v - (float)h);
}

// ---------------------------------------------------------------------------
// Transpose+split: src fp32 [K][N] -> dst fp16 hi/lo [N][K]
__global__ __launch_bounds__(256) void wtconvh_kernel(
    const float* __restrict__ src, _Float16* __restrict__ dh, _Float16* __restrict__ dl,
    int K, int N)
{
    __shared__ float tile[32][33];
    int n0 = blockIdx.x * 32, k0 = blockIdx.y * 32;
    int tx = threadIdx.x & 31, ty = threadIdx.x >> 5;
#pragma unroll
    for (int i = 0; i < 4; ++i)
        tile[ty + 8 * i][tx] = src[(size_t)(k0 + ty + 8 * i) * N + n0 + tx];
    __syncthreads();
#pragma unroll
    for (int i = 0; i < 4; ++i) {
        float v = tile[tx][ty + 8 * i];
        _Float16 h = (_Float16)v;
        size_t idx = (size_t)(n0 + ty + 8 * i) * K + k0 + tx;
        dh[idx] = h;
        dl[idx] = (_Float16)(v - (float)h);
    }
}

// ---------------------------------------------------------------------------
// Transpose+convert fp32 [K][N] -> bf16 [N][K]; single matrix
__global__ __launch_bounds__(256) void wtconv_kernel(
    const float* __restrict__ src, bf16* __restrict__ dst, int K, int N)
{
    __shared__ float tile[32][33];
    int n0 = blockIdx.x * 32, k0 = blockIdx.y * 32;
    int tx = threadIdx.x & 31, ty = threadIdx.x >> 5;
#pragma unroll
    for (int i = 0; i < 4; ++i)
        tile[ty + 8 * i][tx] = src[(size_t)(k0 + ty + 8 * i) * N + n0 + tx];
    __syncthreads();
#pragma unroll
    for (int i = 0; i < 4; ++i)
        dst[(size_t)(n0 + ty + 8 * i) * K + k0 + tx] = f2b(tile[tx][ty + 8 * i]);
}

// Batched variant: blockIdx.z = expert; src/dst strided per expert.
__global__ __launch_bounds__(256) void wtconvb_kernel(
    const float* __restrict__ src, bf16* __restrict__ dst, int K, int N)
{
    int e = blockIdx.z;
    const float* s = src + (size_t)e * K * N;
    bf16* d = dst + (size_t)e * K * N;
    __shared__ float tile[32][33];
    int n0 = blockIdx.x * 32, k0 = blockIdx.y * 32;
    int tx = threadIdx.x & 31, ty = threadIdx.x >> 5;
#pragma unroll
    for (int i = 0; i < 4; ++i)
        tile[ty + 8 * i][tx] = s[(size_t)(k0 + ty + 8 * i) * N + n0 + tx];
    __syncthreads();
#pragma unroll
    for (int i = 0; i < 4; ++i)
        d[(size_t)(n0 + ty + 8 * i) * K + k0 + tx] = f2b(tile[tx][ty + 8 * i]);
}

__global__ void biaspack_kernel(const float* __restrict__ qb, const float* __restrict__ kb,
                                const float* __restrict__ vb, float* __restrict__ dst) {
    int i = blockIdx.x * 256 + threadIdx.x;   // 3072
    dst[i] = i < 1024 ? qb[i] : (i < 2048 ? kb[i - 1024] : vb[i - 2048]);
}

// ---------------------------------------------------------------------------
// Split-fp16 single-pass GEMM: C = (Ah+Al)@(Bh+Bl)^T + bias  (drops Al*Bl)
// ASYNC staging (proven round 13).
template<int EPI>
__global__ __launch_bounds__(256) void mmsplit_kernel(
    const _Float16* __restrict__ Ah, const _Float16* __restrict__ Al,
    const _Float16* __restrict__ Bh, const _Float16* __restrict__ Bl,
    const float* __restrict__ bias, float* __restrict__ C,
    _Float16* __restrict__ Ch, _Float16* __restrict__ Cl,
    int M, int N, int K)
{
    __shared__ char smem[65536];
    const int tid = threadIdx.x;
    const int lane = tid & 63, wave = tid >> 6;
    const int wm = wave >> 1, wn = wave & 1;
    const int bm = blockIdx.y * 128, bn = blockIdx.x * 128;
    const int l15 = lane & 15, l4 = lane >> 4;
    const int srow = tid >> 3;
    const int sc = tid & 7;

    f32x4 acc[4][4];
#pragma unroll
    for (int i = 0; i < 4; ++i)
#pragma unroll
        for (int j = 0; j < 4; ++j) acc[i][j] = 0.f;

    for (int k0 = 0; k0 < K; k0 += 64) {
#pragma unroll
        for (int p = 0; p < 4; ++p) {
            int row = p * 32 + srow;
            int gsw = (sc ^ (row & 7)) * 8;       // inverse-swizzled k offset
            size_t ga = (size_t)(bm + row) * K + k0 + gsw;
            size_t gb = (size_t)(bn + row) * K + k0 + gsw;
            int ldst = p * 4096 + tid * 16;       // linear: row*128 + sc*16
            async16(smem + ldst,         Ah + ga);
            async16(smem + 16384 + ldst, Al + ga);
            async16(smem + 32768 + ldst, Bh + gb);
            async16(smem + 49152 + ldst, Bl + gb);
        }
        __syncthreads();
#pragma unroll
        for (int kk = 0; kk < 2; ++kk) {
            f16x8 afh[4], afl[4], bfh[4], bfl[4];
            int g = kk * 4 + l4;
#pragma unroll
            for (int mi = 0; mi < 4; ++mi) {
                int row = wm * 64 + mi * 16 + l15;
                int o = row * 128 + ((g ^ (row & 7)) << 4);
                afh[mi] = *(const f16x8*)(smem + o);
                afl[mi] = *(const f16x8*)(smem + 16384 + o);
            }
#pragma unroll
            for (int ni = 0; ni < 4; ++ni) {
                int row = wn * 64 + ni * 16 + l15;
                int o = row * 128 + ((g ^ (row & 7)) << 4);
                bfh[ni] = *(const f16x8*)(smem + 32768 + o);
                bfl[ni] = *(const f16x8*)(smem + 49152 + o);
            }
#pragma unroll
            for (int mi = 0; mi < 4; ++mi)
#pragma unroll
                for (int ni = 0; ni < 4; ++ni) {
                    acc[mi][ni] = __builtin_amdgcn_mfma_f32_16x16x32_f16(
                        afh[mi], bfh[ni], acc[mi][ni], 0, 0, 0);
                    acc[mi][ni] = __builtin_amdgcn_mfma_f32_16x16x32_f16(
                        afh[mi], bfl[ni], acc[mi][ni], 0, 0, 0);
                    acc[mi][ni] = __builtin_amdgcn_mfma_f32_16x16x32_f16(
                        afl[mi], bfh[ni], acc[mi][ni], 0, 0, 0);
                }
        }
        __syncthreads();
    }
#pragma unroll
    for (int ni = 0; ni < 4; ++ni) {
        int col = bn + wn * 64 + ni * 16 + l15;
        float bv = bias[col];
#pragma unroll
        for (int mi = 0; mi < 4; ++mi)
#pragma unroll
            for (int rr = 0; rr < 4; ++rr) {
                int row = bm + wm * 64 + mi * 16 + l4 * 4 + rr;
                float v = acc[mi][ni][rr] + bv;
                size_t idx = (size_t)row * N + col;
                if (EPI == 0) {
                    C[idx] = v;
                } else {
                    v = fmaxf(v, 0.f);
                    _Float16 h = (_Float16)v;
                    Ch[idx] = h;
                    Cl[idx] = (_Float16)(v - (float)h);
                }
            }
    }
}

// ---------------------------------------------------------------------------
// Vocab GEMM: bf16 MFMA, 128x128, N-fastest grid (best write locality),
// async staging, NONTEMPORAL C stores (bypass L3 so B stays resident).
__global__ __launch_bounds__(256) void mmv_kernel(
    const bf16* __restrict__ A, const bf16* __restrict__ BT,
    const float* __restrict__ bias, float* __restrict__ C,
    int M, int N, int K)
{
    const int bm = blockIdx.y * 128;
    const int bn = blockIdx.x * 128;
    __shared__ char smem[32768];
    const int tid = threadIdx.x;
    const int lane = tid & 63, wave = tid >> 6;
    const int wm = wave >> 1, wn = wave & 1;
    const int l15 = lane & 15, l4 = lane >> 4;
    const int srow = tid >> 3;
    const int sc = tid & 7;

    f32x4 acc[4][4];
#pragma unroll
    for (int i = 0; i < 4; ++i)
#pragma unroll
        for (int j = 0; j < 4; ++j) acc[i][j] = 0.f;

    for (int k0 = 0; k0 < K; k0 += 64) {
#pragma unroll
        for (int p = 0; p < 4; ++p) {
            int row = p * 32 + srow;
            int gsw = (sc ^ (row & 7)) * 8;
            int ldst = p * 4096 + tid * 16;
            async16(smem + ldst,         A + (size_t)(bm + row) * K + k0 + gsw);
            async16(smem + 16384 + ldst, BT + (size_t)(bn + row) * K + k0 + gsw);
        }
        __syncthreads();
#pragma unroll
        for (int kk = 0; kk < 2; ++kk) {
            bf16x8 af[4], bfv[4];
            int g = kk * 4 + l4;
#pragma unroll
            for (int mi = 0; mi < 4; ++mi) {
                int row = wm * 64 + mi * 16 + l15;
                af[mi] = *(const bf16x8*)(smem + row * 128 + ((g ^ (row & 7)) << 4));
            }
#pragma unroll
            for (int ni = 0; ni < 4; ++ni) {
                int row = wn * 64 + ni * 16 + l15;
                bfv[ni] = *(const bf16x8*)(smem + 16384 + row * 128 + ((g ^ (row & 7)) << 4));
            }
#pragma unroll
            for (int mi = 0; mi < 4; ++mi)
#pragma unroll
                for (int ni = 0; ni < 4; ++ni)
                    acc[mi][ni] = __builtin_amdgcn_mfma_f32_16x16x32_bf16(
                        af[mi], bfv[ni], acc[mi][ni], 0, 0, 0);
        }
        __syncthreads();
    }
#pragma unroll
    for (int ni = 0; ni < 4; ++ni) {
        int col = bn + wn * 64 + ni * 16 + l15;
        float bv = bias[col];
#pragma unroll
        for (int mi = 0; mi < 4; ++mi)
#pragma unroll
            for (int rr = 0; rr < 4; ++rr) {
                int row = bm + wm * 64 + mi * 16 + l4 * 4 + rr;
                __builtin_nontemporal_store(acc[mi][ni][rr] + bv,
                                            &C[(size_t)row * N + col]);
            }
    }
}

// ---------------------------------------------------------------------------
// MoE routing
__global__ void route_kernel(const float* __restrict__ we,
                             int* __restrict__ cnt, int* __restrict__ lists) {
    int e = blockIdx.x;
    __shared__ int lcnt;
    if (threadIdx.x == 0) lcnt = 0;
    __syncthreads();
    for (int t = threadIdx.x; t < NT; t += 256) {
        if (we[t * 8 + e] != 0.f) {
            int pos = atomicAdd(&lcnt, 1);
            lists[e * NT + pos] = t;
        }
    }
    __syncthreads();
    if (threadIdx.x == 0) cnt[e] = lcnt;
}

// ---------------------------------------------------------------------------
// Batched gathered expert FFN-1 (async staging; writes expert-disjoint).
__global__ __launch_bounds__(256) void mmg1b_kernel(
    const bf16* __restrict__ A, const bf16* __restrict__ e1tall,
    const float* __restrict__ eb1, bf16* __restrict__ hcall,
    const int* __restrict__ lists, const int* __restrict__ cnt)
{
    const int e = blockIdx.y >> 4;
    const int m = min(cnt[e], ECAP);
    const int bm = (blockIdx.y & 15) * 128;
    if (bm >= m) return;
    const bf16* BT = e1tall + (size_t)e * NDFF * ND;
    const float* bias = eb1 + e * NDFF;
    bf16* Cc = hcall + (size_t)e * ECAP * NDFF;
    __shared__ char smem[32768];
    const int tid = threadIdx.x;
    const int lane = tid & 63, wave = tid >> 6;
    const int wm = wave >> 1, wn = wave & 1;
    const int bn = blockIdx.x * 128;
    const int l15 = lane & 15, l4 = lane >> 4;
    const int srow = tid >> 3;
    const int sc = tid & 7;
    const int* lst = lists + e * NT;
    const int K = 1024, N = NDFF;
    int trow[4];
#pragma unroll
    for (int p = 0; p < 4; ++p) {
        int gr = bm + p * 32 + srow;
        trow[p] = lst[gr < m ? gr : m - 1];
    }

    f32x4 acc[4][4];
#pragma unroll
    for (int i = 0; i < 4; ++i)
#pragma unroll
        for (int j = 0; j < 4; ++j) acc[i][j] = 0.f;

    for (int k0 = 0; k0 < K; k0 += 64) {
#pragma unroll
        for (int p = 0; p < 4; ++p) {
            int row = p * 32 + srow;
            int gsw = (sc ^ (row & 7)) * 8;
            int ldst = p * 4096 + tid * 16;
            async16(smem + ldst,         A + (size_t)trow[p] * K + k0 + gsw);
            async16(smem + 16384 + ldst, BT + (size_t)(bn + row) * K + k0 + gsw);
        }
        __syncthreads();
#pragma unroll
        for (int kk = 0; kk < 2; ++kk) {
            bf16x8 af[4], bfv[4];
            int g = kk * 4 + l4;
#pragma unroll
            for (int mi = 0; mi < 4; ++mi) {
                int row = wm * 64 + mi * 16 + l15;
                af[mi] = *(const bf16x8*)(smem + row * 128 + ((g ^ (row & 7)) << 4));
            }
#pragma unroll
            for (int ni = 0; ni < 4; ++ni) {
                int row = wn * 64 + ni * 16 + l15;
                bfv[ni] = *(const bf16x8*)(smem + 16384 + row * 128 + ((g ^ (row & 7)) << 4));
            }
#pragma unroll
            for (int mi = 0; mi < 4; ++mi)
#pragma unroll
                for (int ni = 0; ni < 4; ++ni)
                    acc[mi][ni] = __builtin_amdgcn_mfma_f32_16x16x32_bf16(
                        af[mi], bfv[ni], acc[mi][ni], 0, 0, 0);
        }
        __syncthreads();
    }
#pragma unroll
    for (int ni = 0; ni < 4; ++ni) {
        int col = bn + wn * 64 + ni * 16 + l15;
        float bv = bias[col];
#pragma unroll
        for (int mi = 0; mi < 4; ++mi)
#pragma unroll
            for (int rr = 0; rr < 4; ++rr) {
                int row = bm + wm * 64 + mi * 16 + l4 * 4 + rr;
                if (row < m)
                    Cc[(size_t)row * N + col] = f2b(fmaxf(acc[mi][ni][rr] + bv, 0.f));
            }
    }
}

// ---------------------------------------------------------------------------
// Batched expert FFN-2 + scatter (async staging; atomicAdd for the 2-expert
// overlap; two adds onto exact zero are order-independent bitwise).
__global__ __launch_bounds__(256) void mmg2b_kernel(
    const bf16* __restrict__ hcall, const bf16* __restrict__ e2tall,
    const float* __restrict__ eb2, float* __restrict__ macc,
    const float* __restrict__ we,
    const int* __restrict__ lists, const int* __restrict__ cnt)
{
    const int e = blockIdx.y >> 4;
    const int m = min(cnt[e], ECAP);
    const int bm = (blockIdx.y & 15) * 128;
    if (bm >= m) return;
    const bf16* Ac = hcall + (size_t)e * ECAP * NDFF;
    const bf16* BT = e2tall + (size_t)e * ND * NDFF;
    const float* bias = eb2 + e * ND;
    __shared__ char smem[32768];
    const int tid = threadIdx.x;
    const int lane = tid & 63, wave = tid >> 6;
    const int wm = wave >> 1, wn = wave & 1;
    const int bn = blockIdx.x * 128;
    const int l15 = lane & 15, l4 = lane >> 4;
    const int srow = tid >> 3;
    const int sc = tid & 7;
    const int* lst = lists + e * NT;
    const int K = NDFF, N = ND;

    f32x4 acc[4][4];
#pragma unroll
    for (int i = 0; i < 4; ++i)
#pragma unroll
        for (int j = 0; j < 4; ++j) acc[i][j] = 0.f;

    for (int k0 = 0; k0 < K; k0 += 64) {
#pragma unroll
        for (int p = 0; p < 4; ++p) {
            int row = p * 32 + srow;
            int ar = bm + row; ar = ar < m ? ar : m - 1;
            int gsw = (sc ^ (row & 7)) * 8;
            int ldst = p * 4096 + tid * 16;
            async16(smem + ldst,         Ac + (size_t)ar * K + k0 + gsw);
            async16(smem + 16384 + ldst, BT + (size_t)(bn + row) * K + k0 + gsw);
        }
        __syncthreads();
#pragma unroll
        for (int kk = 0; kk < 2; ++kk) {
            bf16x8 af[4], bfv[4];
            int g = kk * 4 + l4;
#pragma unroll
            for (int mi = 0; mi < 4; ++mi) {
                int row = wm * 64 + mi * 16 + l15;
                af[mi] = *(const bf16x8*)(smem + row * 128 + ((g ^ (row & 7)) << 4));
            }
#pragma unroll
            for (int ni = 0; ni < 4; ++ni) {
                int row = wn * 64 + ni * 16 + l15;
                bfv[ni] = *(const bf16x8*)(smem + 16384 + row * 128 + ((g ^ (row & 7)) << 4));
            }
#pragma unroll
            for (int mi = 0; mi < 4; ++mi)
#pragma unroll
                for (int ni = 0; ni < 4; ++ni)
                    acc[mi][ni] = __builtin_amdgcn_mfma_f32_16x16x32_bf16(
                        af[mi], bfv[ni], acc[mi][ni], 0, 0, 0);
        }
        __syncthreads();
    }
#pragma unroll
    for (int ni = 0; ni < 4; ++ni) {
        int col = bn + wn * 64 + ni * 16 + l15;
        float bv = bias[col];
#pragma unroll
        for (int mi = 0; mi < 4; ++mi)
#pragma unroll
            for (int rr = 0; rr < 4; ++rr) {
                int row = bm + wm * 64 + mi * 16 + l4 * 4 + rr;
                if (row < m) {
                    int t = lst[row];
                    atomicAdd(&macc[(size_t)t * N + col],
                              we[t * 8 + e] * (acc[mi][ni][rr] + bv));
                }
            }
    }
}

// ---------------------------------------------------------------------------
// RoPE + head-pack split (proven round 9)
__global__ __launch_bounds__(256) void ropehs_kernel(
    const float* __restrict__ qkv, const float* __restrict__ c, const float* __restrict__ sn,
    _Float16* __restrict__ Qh, _Float16* __restrict__ Ql,
    _Float16* __restrict__ Kh, _Float16* __restrict__ Kl,
    _Float16* __restrict__ VTh, _Float16* __restrict__ VTl)
{
    int st = blockIdx.x, bh = blockIdx.y;
    int b = bh >> 4, h = bh & 15;
    int s0 = st * 64;
    int tid = threadIdx.x;
#pragma unroll
    for (int it = 0; it < 8; ++it) {
        int idx = tid + 256 * it;       // 64 s x 32 j
        int sl = idx >> 5, j = idx & 31;
        int s = s0 + sl;
        size_t t = (size_t)b * NS + s;
        float cv = c[s * 32 + j], sv = sn[s * 32 + j];
        const float* base = qkv + t * 3072 + h * 64;
        float q1 = base[j], q2 = base[32 + j];
        float k1 = base[1024 + j], k2 = base[1024 + 32 + j];
        float qr1 = (q1 * cv - q2 * sv) * 0.125f;
        float qr2 = (q2 * cv + q1 * sv) * 0.125f;
        float kr1 = k1 * cv - k2 * sv;
        float kr2 = k2 * cv + k1 * sv;
        size_t o = (size_t)bh * 65536 + (size_t)s * 64;
        _Float16 hh1 = (_Float16)qr1, hh2 = (_Float16)qr2;
        Qh[o + j] = hh1;      Ql[o + j] = (_Float16)(qr1 - (float)hh1);
        Qh[o + 32 + j] = hh2; Ql[o + 32 + j] = (_Float16)(qr2 - (float)hh2);
        _Float16 kh1 = (_Float16)kr1, kh2 = (_Float16)kr2;
        Kh[o + j] = kh1;      Kl[o + j] = (_Float16)(kr1 - (float)kh1);
        Kh[o + 32 + j] = kh2; Kl[o + 32 + j] = (_Float16)(kr2 - (float)kh2);
    }
    __shared__ float vt[64][65];
    int dl = tid & 63, sq = tid >> 6;
#pragma unroll
    for (int i = 0; i < 16; ++i) {
        int sl = sq + 4 * i;
        size_t t = (size_t)b * NS + s0 + sl;
        vt[sl][dl] = qkv[t * 3072 + 2048 + h * 64 + dl];
    }
    __syncthreads();
#pragma unroll
    for (int i = 0; i < 16; ++i) {
        int d = sq + 4 * i;
        float v = vt[dl][d];
        _Float16 hv = (_Float16)v;
        size_t o = (size_t)bh * 65536 + (size_t)d * 1024 + s0 + dl;
        VTh[o] = hv;
        VTl[o] = (_Float16)(v - (float)hv);
    }
}

// ---------------------------------------------------------------------------
// Scores (proven round 9)
__global__ __launch_bounds__(256) void scores_kernel(
    const _Float16* __restrict__ Qh, const _Float16* __restrict__ Ql,
    const _Float16* __restrict__ Kh, const _Float16* __restrict__ Kl,
    float* __restrict__ S)
{
    int bh = blockIdx.z;
    int q0 = blockIdx.y * 128, k0 = blockIdx.x * 128;
    int lane = threadIdx.x & 63, wave = threadIdx.x >> 6;
    int wm = wave >> 1, wn = wave & 1;
    int l15 = lane & 15, l4 = lane >> 4;
    size_t hb_ = (size_t)bh * 65536;
    f32x4 acc[4][4];
#pragma unroll
    for (int i = 0; i < 4; ++i)
#pragma unroll
        for (int j = 0; j < 4; ++j) acc[i][j] = 0.f;
#pragma unroll
    for (int kk = 0; kk < 2; ++kk) {
        f16x8 ah[4], al[4], bh2[4], bl[4];
#pragma unroll
        for (int mi = 0; mi < 4; ++mi) {
            size_t o = hb_ + (size_t)(q0 + wm * 64 + mi * 16 + l15) * 64 + kk * 32 + l4 * 8;
            ah[mi] = *(const f16x8*)(Qh + o);
            al[mi] = *(const f16x8*)(Ql + o);
        }
#pragma unroll
        for (int ni = 0; ni < 4; ++ni) {
            size_t o = hb_ + (size_t)(k0 + wn * 64 + ni * 16 + l15) * 64 + kk * 32 + l4 * 8;
            bh2[ni] = *(const f16x8*)(Kh + o);
            bl[ni]  = *(const f16x8*)(Kl + o);
        }
#pragma unroll
        for (int mi = 0; mi < 4; ++mi)
#pragma unroll
            for (int ni = 0; ni < 4; ++ni) {
                acc[mi][ni] = __builtin_amdgcn_mfma_f32_16x16x32_f16(ah[mi], bh2[ni], acc[mi][ni], 0, 0, 0);
                acc[mi][ni] = __builtin_amdgcn_mfma_f32_16x16x32_f16(ah[mi], bl[ni],  acc[mi][ni], 0, 0, 0);
                acc[mi][ni] = __builtin_amdgcn_mfma_f32_16x16x32_f16(al[mi], bh2[ni], acc[mi][ni], 0, 0, 0);
            }
    }
    float* Sb = S + (size_t)bh * 1048576;
#pragma unroll
    for (int mi = 0; mi < 4; ++mi)
#pragma unroll
        for (int ni = 0; ni < 4; ++ni)
#pragma unroll
            for (int rr = 0; rr < 4; ++rr)
                Sb[(size_t)(q0 + wm * 64 + mi * 16 + l4 * 4 + rr) * 1024 + k0 + wn * 64 + ni * 16 + l15] =
                    acc[mi][ni][rr];
}

// ---------------------------------------------------------------------------
// Softmax -> packed fp16 hi|lo P (proven round 9)
__global__ __launch_bounds__(256) void softmaxp_kernel(float* __restrict__ S) {
    int row = blockIdx.x * 4 + (threadIdx.x >> 6);   // 32768 rows
    int lane = threadIdx.x & 63;
    float* Srow = S + (size_t)row * 1024;
    float f[16];
#pragma unroll
    for (int i = 0; i < 4; ++i) {
        float4 v = *(const float4*)(Srow + lane * 16 + i * 4);
        f[i * 4 + 0] = v.x; f[i * 4 + 1] = v.y; f[i * 4 + 2] = v.z; f[i * 4 + 3] = v.w;
    }
    float m = -1e30f;
#pragma unroll
    for (int j = 0; j < 16; ++j) m = fmaxf(m, f[j]);
#pragma unroll
    for (int off = 32; off; off >>= 1) m = fmaxf(m, __shfl_xor(m, off));
    float s = 0.f;
#pragma unroll
    for (int j = 0; j < 16; ++j) { f[j] = __expf(f[j] - m); s += f[j]; }
#pragma unroll
    for (int off = 32; off; off >>= 1) s += __shfl_xor(s, off);
    float inv = 1.f / s;
    f16x8 ph[2], pl[2];
#pragma unroll
    for (int j = 0; j < 16; ++j) {
        float p = f[j] * inv;
        _Float16 h = (_Float16)p;
        ph[j >> 3][j & 7] = h;
        pl[j >> 3][j & 7] = (_Float16)(p - (float)h);
    }
    _Float16* Pr = (_Float16*)Srow;
    *(f16x8*)(Pr + lane * 16) = ph[0];
    *(f16x8*)(Pr + lane * 16 + 8) = ph[1];
    *(f16x8*)(Pr + 1024 + lane * 16) = pl[0];
    *(f16x8*)(Pr + 1024 + lane * 16 + 8) = pl[1];
}

// ---------------------------------------------------------------------------
// PV (proven round 9)
__global__ __launch_bounds__(256) void pv_kernel(
    const float* __restrict__ Sp,
    const _Float16* __restrict__ VTh, const _Float16* __restrict__ VTl,
    _Float16* __restrict__ oh, _Float16* __restrict__ ol)
{
    int q0 = blockIdx.x * 64;
    int bh = blockIdx.y;
    int b = bh >> 4, h = bh & 15;
    int lane = threadIdx.x & 63, wave = threadIdx.x >> 6;
    int wm = wave >> 1, wn = wave & 1;
    int l15 = lane & 15, l4 = lane >> 4;
    const _Float16* Pb = (const _Float16*)(Sp + (size_t)bh * 1048576);
    size_t vb_ = (size_t)bh * 65536;
    f32x4 acc[2][2];
    acc[0][0] = 0.f; acc[0][1] = 0.f; acc[1][0] = 0.f; acc[1][1] = 0.f;
    for (int kv = 0; kv < 1024; kv += 32) {
        f16x8 ah[2], al[2], bh2[2], bl[2];
#pragma unroll
        for (int mi = 0; mi < 2; ++mi) {
            const _Float16* pr = Pb + (size_t)(q0 + wm * 32 + mi * 16 + l15) * 2048 + kv + l4 * 8;
            ah[mi] = *(const f16x8*)pr;
            al[mi] = *(const f16x8*)(pr + 1024);
        }
#pragma unroll
        for (int ni = 0; ni < 2; ++ni) {
            size_t o = vb_ + (size_t)(wn * 32 + ni * 16 + l15) * 1024 + kv + l4 * 8;
            bh2[ni] = *(const f16x8*)(VTh + o);
            bl[ni]  = *(const f16x8*)(VTl + o);
        }
#pragma unroll
        for (int mi = 0; mi < 2; ++mi)
#pragma unroll
            for (int ni = 0; ni < 2; ++ni) {
                acc[mi][ni] = __builtin_amdgcn_mfma_f32_16x16x32_f16(ah[mi], bh2[ni], acc[mi][ni], 0, 0, 0);
                acc[mi][ni] = __builtin_amdgcn_mfma_f32_16x16x32_f16(ah[mi], bl[ni],  acc[mi][ni], 0, 0, 0);
                acc[mi][ni] = __builtin_amdgcn_mfma_f32_16x16x32_f16(al[mi], bh2[ni], acc[mi][ni], 0, 0, 0);
            }
    }
#pragma unroll
    for (int mi = 0; mi < 2; ++mi)
#pragma unroll
        for (int ni = 0; ni < 2; ++ni)
#pragma unroll
            for (int rr = 0; rr < 4; ++rr) {
                int qrow = q0 + wm * 32 + mi * 16 + l4 * 4 + rr;
                int d = wn * 32 + ni * 16 + l15;
                size_t idx = ((size_t)(b * NS + qrow)) * ND + h * 64 + d;
                float v = acc[mi][ni][rr];
                _Float16 hv = (_Float16)v;
                oh[idx] = hv;
                ol[idx] = (_Float16)(v - (float)hv);
            }
}

// ---------------------------------------------------------------------------
// Residual + LayerNorm with fused outputs: fp32, fp16 hi/lo split, bf16.
__global__ __launch_bounds__(256) void ln_kernel(
    const float* __restrict__ res, const float* __restrict__ y,
    const float* __restrict__ g, const float* __restrict__ b,
    float* __restrict__ outf,
    _Float16* __restrict__ dh, _Float16* __restrict__ dl,
    bf16* __restrict__ outb)
{
    int t = blockIdx.x, tid = threadIdx.x;
    size_t base = (size_t)t * ND;
    float v[4];
    float s = 0.f, s2 = 0.f;
#pragma unroll
    for (int i = 0; i < 4; ++i) {
        int d = tid + 256 * i;
        float val = y[base + d];
        if (res) val += res[base + d];
        v[i] = val;
        s += val;
        s2 += val * val;
    }
    for (int off = 32; off; off >>= 1) {
        s  += __shfl_xor(s, off);
        s2 += __shfl_xor(s2, off);
    }
    __shared__ float rs[4], rs2[4];
    int wave = tid >> 6, lane = tid & 63;
    if (!lane) { rs[wave] = s; rs2[wave] = s2; }
    __syncthreads();
    s = rs[0] + rs[1] + rs[2] + rs[3];
    s2 = rs2[0] + rs2[1] + rs2[2] + rs2[3];
    float mu = s / ND;
    float var = s2 / ND - mu * mu;
    float rstd = rsqrtf(var + 1e-5f);
#pragma unroll
    for (int i = 0; i < 4; ++i) {
        int d = tid + 256 * i;
        float val = (v[i] - mu) * rstd * g[d] + b[d];
        if (outf) outf[base + d] = val;
        if (dh) {
            _Float16 h = (_Float16)val;
            dh[base + d] = h;
            dl[base + d] = (_Float16)(val - (float)h);
        }
        if (outb) outb[base + d] = f2b(val);
    }
}

// ---------------------------------------------------------------------------
__global__ __launch_bounds__(256) void gate_kernel(
    const float* __restrict__ x, const float* __restrict__ gw,
    const float* __restrict__ gb, float* __restrict__ we)
{
    int t = blockIdx.x, tid = threadIdx.x;
    float acc[8] = {};
#pragma unroll
    for (int i = 0; i < 4; ++i) {
        int d = tid * 4 + i;
        float xv = x[(size_t)t * ND + d];
#pragma unroll
        for (int e = 0; e < 8; ++e) acc[e] += xv * gw[d * 8 + e];
    }
    for (int off = 32; off; off >>= 1)
#pragma unroll
        for (int e = 0; e < 8; ++e) acc[e] += __shfl_xor(acc[e], off);
    __shared__ float red[4][8];
    int wave = tid >> 6, lane = tid & 63;
    if (!lane)
#pragma unroll
        for (int e = 0; e < 8; ++e) red[wave][e] = acc[e];
    __syncthreads();
    if (tid == 0) {
        float lg[8];
#pragma unroll
        for (int e = 0; e < 8; ++e)
            lg[e] = red[0][e] + red[1][e] + red[2][e] + red[3][e] + gb[e];
        int i1 = 0;
        for (int e = 1; e < 8; ++e) if (lg[e] > lg[i1]) i1 = e;
        int i2 = -1;
        for (int e = 0; e < 8; ++e) if (e != i1 && (i2 < 0 || lg[e] > lg[i2])) i2 = e;
        float e2 = __expf(lg[i2] - lg[i1]);
        float denom = 1.f + e2;
#pragma unroll
        for (int e = 0; e < 8; ++e) we[t * 8 + e] = 0.f;
        we[t * 8 + i1] = 1.f / denom;
        we[t * 8 + i2] = e2 / denom;
    }
}

__global__ void zero_kernel(float* __restrict__ p, int n) {
    int i = blockIdx.x * blockDim.x + threadIdx.x;
    if (i < n) p[i] = 0.f;
}

// ---------------------------------------------------------------------------
extern "C" void kernel_launch(void* const* d_in, const int* in_sizes, int n_in,
                              void* d_out, int out_size, void* d_ws, size_t ws_size,
                              hipStream_t stream) {
    (void)in_sizes; (void)n_in; (void)out_size; (void)ws_size;
    const int*   src  = (const int*)  d_in[0];
    const float* emb  = (const float*)d_in[1];
    const float* qw   = (const float*)d_in[2];
    const float* qb   = (const float*)d_in[3];
    const float* kw   = (const float*)d_in[4];
    const float* kb   = (const float*)d_in[5];
    const float* vw   = (const float*)d_in[6];
    const float* vb   = (const float*)d_in[7];
    const float* ow   = (const float*)d_in[8];
    const float* ob   = (const float*)d_in[9];
    const float* f1w  = (const float*)d_in[10];
    const float* f1b  = (const float*)d_in[11];
    const float* f2w  = (const float*)d_in[12];
    const float* f2b_ = (const float*)d_in[13];
    const float* ln1g = (const float*)d_in[14];
    const float* ln1b = (const float*)d_in[15];
    const float* ln2g = (const float*)d_in[16];
    const float* ln2b = (const float*)d_in[17];
    const float* gw   = (const float*)d_in[18];
    const float* gb   = (const float*)d_in[19];
    const float* ew1  = (const float*)d_in[20];
    const float* eb1  = (const float*)d_in[21];
    const float* ew2  = (const float*)d_in[22];
    const float* eb2  = (const float*)d_in[23];
    const float* flng = (const float*)d_in[24];
    const float* flnb = (const float*)d_in[25];
    const float* outw = (const float*)d_in[26];
    const float* outb = (const float*)d_in[27];
    float* out = (float*)d_out;

    char* w = (char*)d_ws;
    size_t off = 0;
    auto alloc = [&](size_t bytes) -> char* {
        size_t cur = (off + 255) & ~(size_t)255;
        off = cur + bytes;
        return w + cur;
    };

    float* xbuf   = (float*)alloc((size_t)NT * ND * 4);
    float* qkvbuf = (float*)alloc((size_t)NT * 3072 * 4);
    float* tbuf   = (float*)alloc((size_t)NT * ND * 4);
    float* macc   = (float*)alloc((size_t)NT * ND * 4);
    // ---- span reused post-gate as hcall (88MB, all dead after gate) ----
    _Float16* xh  = (_Float16*)alloc((size_t)NT * ND * 2);
    _Float16* xl  = (_Float16*)alloc((size_t)NT * ND * 2);
    _Float16* oh  = (_Float16*)alloc((size_t)NT * ND * 2);
    _Float16* ol  = (_Float16*)alloc((size_t)NT * ND * 2);
    _Float16* wqkvh = (_Float16*)alloc((size_t)3072 * ND * 2);
    _Float16* wqkvl = (_Float16*)alloc((size_t)3072 * ND * 2);
    _Float16* woh = (_Float16*)alloc((size_t)ND * ND * 2);
    _Float16* wol = (_Float16*)alloc((size_t)ND * ND * 2);
    _Float16* w1h = (_Float16*)alloc((size_t)ND * NDFF * 2);
    _Float16* w1l = (_Float16*)alloc((size_t)ND * NDFF * 2);
    _Float16* w2h = (_Float16*)alloc((size_t)ND * NDFF * 2);
    _Float16* w2l = (_Float16*)alloc((size_t)ND * NDFF * 2);
    _Float16* Qhh = (_Float16*)alloc((size_t)32 * NS * 64 * 2);
    _Float16* Qll = (_Float16*)alloc((size_t)32 * NS * 64 * 2);
    _Float16* Khh = (_Float16*)alloc((size_t)32 * NS * 64 * 2);
    _Float16* Kll = (_Float16*)alloc((size_t)32 * NS * 64 * 2);
    _Float16* VTh = (_Float16*)alloc((size_t)32 * 64 * NS * 2);
    _Float16* VTl = (_Float16*)alloc((size_t)32 * 64 * NS * 2);
    // --------------------------------------------------------------------
    float* webuf  = (float*)alloc((size_t)NT * NE * 4);
    float* cbuf   = (float*)alloc((size_t)NS * 32 * 4);
    float* snbuf  = (float*)alloc((size_t)NS * 32 * 4);
    float* qkvbias = (float*)alloc(3072 * 4);
    int*   ecnt   = (int*)alloc(NE * 4);
    int*   elists = (int*)alloc((size_t)NE * NT * 4);
    bf16*  xb     = (bf16*)alloc((size_t)NT * ND * 2);
    bf16*  lnout  = (bf16*)alloc((size_t)NT * ND * 2);
    bf16*  outwt  = (bf16*)alloc((size_t)NV * ND * 2);       // 62.5MB
    char*  Sbig   = alloc(134217728);                        // 128MB

    float* Sbuf = (float*)Sbig;                    // attention phase
    _Float16* hh = (_Float16*)(Sbig + 33554432);   // FFN [32,48MB)
    _Float16* hl = (_Float16*)(Sbig + 50331648);   // FFN [48,64MB)
    bf16* e1tall = (bf16*)Sbig;                    // post-gate [0,64MB)
    bf16* e2tall = (bf16*)(Sbig + 67108864);       // post-gate [64,128MB)
    bf16* hcall  = (bf16*)xh;                      // 8 x ECAP x 4096 bf16 = 80MB

    const int NX = NT * ND;
    yarn_kernel<<<(NS * 32) / 256, 256, 0, stream>>>(cbuf, snbuf);
    embed_kernel<<<NX / 256, 256, 0, stream>>>(src, emb, xbuf, xh, xl);

    for (int l = 0; l < NL; ++l) {
        wtconvh_kernel<<<dim3(32, 32), 256, 0, stream>>>(qw + (size_t)l * 1048576, wqkvh, wqkvl, 1024, 1024);
        wtconvh_kernel<<<dim3(32, 32), 256, 0, stream>>>(kw + (size_t)l * 1048576, wqkvh + 1048576, wqkvl + 1048576, 1024, 1024);
        wtconvh_kernel<<<dim3(32, 32), 256, 0, stream>>>(vw + (size_t)l * 1048576, wqkvh + 2097152, wqkvl + 2097152, 1024, 1024);
        wtconvh_kernel<<<dim3(32, 32), 256, 0, stream>>>(ow + (size_t)l * 1048576, woh, wol, 1024, 1024);
        wtconvh_kernel<<<dim3(128, 32), 256, 0, stream>>>(f1w + (size_t)l * 4194304, w1h, w1l, 1024, 4096);
        wtconvh_kernel<<<dim3(32, 128), 256, 0, stream>>>(f2w + (size_t)l * 4194304, w2h, w2l, 4096, 1024);
        biaspack_kernel<<<12, 256, 0, stream>>>(qb + l * 1024, kb + l * 1024, vb + l * 1024, qkvbias);

        mmsplit_kernel<0><<<dim3(24, 16), 256, 0, stream>>>(xh, xl, wqkvh, wqkvl, qkvbias, qkvbuf, nullptr, nullptr, NT, 3072, 1024);
        ropehs_kernel<<<dim3(16, 32), 256, 0, stream>>>(qkvbuf, cbuf, snbuf, Qhh, Qll, Khh, Kll, VTh, VTl);
        scores_kernel<<<dim3(8, 8, 32), 256, 0, stream>>>(Qhh, Qll, Khh, Kll, Sbuf);
        softmaxp_kernel<<<8192, 256, 0, stream>>>(Sbuf);
        pv_kernel<<<dim3(16, 32), 256, 0, stream>>>(Sbuf, VTh, VTl, oh, ol);
        mmsplit_kernel<0><<<dim3(8, 16), 256, 0, stream>>>(oh, ol, woh, wol, ob + l * 1024, tbuf, nullptr, nullptr, NT, 1024, 1024);
        ln_kernel<<<NT, 256, 0, stream>>>(xbuf, tbuf, ln1g + l * 1024, ln1b + l * 1024, xbuf, xh, xl, nullptr);
        mmsplit_kernel<1><<<dim3(32, 16), 256, 0, stream>>>(xh, xl, w1h, w1l, f1b + l * 4096, nullptr, hh, hl, NT, 4096, 1024);
        mmsplit_kernel<0><<<dim3(8, 16), 256, 0, stream>>>(hh, hl, w2h, w2l, f2b_ + l * 1024, tbuf, nullptr, nullptr, NT, 1024, 4096);
        if (l < NL - 1)
            ln_kernel<<<NT, 256, 0, stream>>>(xbuf, tbuf, ln2g + l * 1024, ln2b + l * 1024, xbuf, xh, xl, nullptr);
        else
            ln_kernel<<<NT, 256, 0, stream>>>(xbuf, tbuf, ln2g + l * 1024, ln2b + l * 1024, xbuf, nullptr, nullptr, xb);
    }

    // Gate on exact fp32 x; route tokens to experts
    gate_kernel<<<NT, 256, 0, stream>>>(xbuf, gw, gb, webuf);
    route_kernel<<<NE, 256, 0, stream>>>(webuf, ecnt, elists);

    // Post-gate: batched sparse expert GEMMs + vocab projection
    zero_kernel<<<NX / 256, 256, 0, stream>>>(macc, NX);
    wtconv_kernel<<<dim3(1000, 32), 256, 0, stream>>>(outw, outwt, 1024, 32000);
    wtconvb_kernel<<<dim3(128, 32, NE), 256, 0, stream>>>(ew1, e1tall, 1024, 4096);
    wtconvb_kernel<<<dim3(32, 128, NE), 256, 0, stream>>>(ew2, e2tall, 4096, 1024);
    mmg1b_kernel<<<dim3(32, 128), 256, 0, stream>>>(xb, e1tall, eb1, hcall, elists, ecnt);
    mmg2b_kernel<<<dim3(8, 128), 256, 0, stream>>>(hcall, e2tall, eb2, macc, webuf, elists, ecnt);
    ln_kernel<<<NT, 256, 0, stream>>>(nullptr, macc, flng, flnb, nullptr, nullptr, nullptr, lnout);
    mmv_kernel<<<dim3(250, 16), 256, 0, stream>>>(lnout, outwt, outb, out, NT, NV, 1024);
}

// Round 17
// 2080.072 us; speedup vs baseline: 1.0091x; 1.0091x over previous
//
#include <hip/hip_runtime.h>
#include <hip/hip_bf16.h>
#include <math.h>

constexpr int NV = 32000, ND = 1024, NH = 16, NHD = 64, NL = 3, NDFF = 4096;
constexpr int NE = 8, NB = 2, NS = 1024, NT = NB * NS;
constexpr int ECAP = 1280;   // per-expert compact-row capacity (expected ~512)

typedef __attribute__((ext_vector_type(8))) short bf16x8;
typedef __attribute__((ext_vector_type(8))) _Float16 f16x8;
typedef __attribute__((ext_vector_type(4))) float f32x4;
typedef __hip_bfloat16 bf16;

__device__ __forceinline__ bf16 f2b(float v) { return __float2bfloat16(v); }

// Async 16B global->LDS (proven bit-identical to reg-staged path, rounds 2-4)
__device__ __forceinline__ void async16(char* lds, const void* g) {
    __builtin_amdgcn_global_load_lds((const __attribute__((address_space(1))) void*)g,
                                     (__attribute__((address_space(3))) void*)lds,
                                     16, 0, 0);
}

// ---------------------------------------------------------------------------
__global__ void yarn_kernel(float* __restrict__ c, float* __restrict__ sn) {
    int idx = blockIdx.x * blockDim.x + threadIdx.x;   // NS*32 threads
    int j = idx & 31;
    int s = idx >> 5;
    double ex = (double)(2 * j) / 64.0;
    double fe = 1.0 / pow(10000.0, ex);
    double fi = fe / 8.0;
    double lin = ((double)j - 8.0) / 13.0;
    double mask = 1.0 - fmin(fmax(lin, 0.0), 1.0);
    double invf = fi * (1.0 - mask) + fe * mask;
    double ms = 0.1 * log(8.0) + 1.0;
    double fr = (double)s * invf;
    c[idx]  = (float)(cos(fr) * ms);
    sn[idx] = (float)(sin(fr) * ms);
}

// ---------------------------------------------------------------------------
__global__ void embed_kernel(const int* __restrict__ src, const float* __restrict__ emb,
                             float* __restrict__ x,
                             _Float16* __restrict__ xh, _Float16* __restrict__ xl) {
    int idx = blockIdx.x * blockDim.x + threadIdx.x;   // NT*ND threads
    int t = idx >> 10;
    int d = idx & 1023;
    int s = src[t];
    s = s < 0 ? 0 : (s > NV - 1 ? NV - 1 : s);
    float v = emb[(size_t)s * ND + d] * 32.0f;
    x[idx] = v;
    _Float16 h = (_Float16)v;
    xh[idx] = h;
    xl[idx] = (_Float16)(v - (float)h);
}

// ---------------------------------------------------------------------------
// Transpose+split: src fp32 [K][N] -> dst fp16 hi/lo [N][K]
__global__ __launch_bounds__(256) void wtconvh_kernel(
    const float* __restrict__ src, _Float16* __restrict__ dh, _Float16* __restrict__ dl,
    int K, int N)
{
    __shared__ float tile[32][33];
    int n0 = blockIdx.x * 32, k0 = blockIdx.y * 32;
    int tx = threadIdx.x & 31, ty = threadIdx.x >> 5;
#pragma unroll
    for (int i = 0; i < 4; ++i)
        tile[ty + 8 * i][tx] = src[(size_t)(k0 + ty + 8 * i) * N + n0 + tx];
    __syncthreads();
#pragma unroll
    for (int i = 0; i < 4; ++i) {
        float v = tile[tx][ty + 8 * i];
        _Float16 h = (_Float16)v;
        size_t idx = (size_t)(n0 + ty + 8 * i) * K + k0 + tx;
        dh[idx] = h;
        dl[idx] = (_Float16)(v - (float)h);
    }
}

// ---------------------------------------------------------------------------
// Transpose+convert fp32 [K][N] -> bf16 [N][K]; single matrix
__global__ __launch_bounds__(256) void wtconv_kernel(
    const float* __restrict__ src, bf16* __restrict__ dst, int K, int N)
{
    __shared__ float tile[32][33];
    int n0 = blockIdx.x * 32, k0 = blockIdx.y * 32;
    int tx = threadIdx.x & 31, ty = threadIdx.x >> 5;
#pragma unroll
    for (int i = 0; i < 4; ++i)
        tile[ty + 8 * i][tx] = src[(size_t)(k0 + ty + 8 * i) * N + n0 + tx];
    __syncthreads();
#pragma unroll
    for (int i = 0; i < 4; ++i)
        dst[(size_t)(n0 + ty + 8 * i) * K + k0 + tx] = f2b(tile[tx][ty + 8 * i]);
}

// Batched variant: blockIdx.z = expert; src/dst strided per expert.
__global__ __launch_bounds__(256) void wtconvb_kernel(
    const float* __restrict__ src, bf16* __restrict__ dst, int K, int N)
{
    int e = blockIdx.z;
    const float* s = src + (size_t)e * K * N;
    bf16* d = dst + (size_t)e * K * N;
    __shared__ float tile[32][33];
    int n0 = blockIdx.x * 32, k0 = blockIdx.y * 32;
    int tx = threadIdx.x & 31, ty = threadIdx.x >> 5;
#pragma unroll
    for (int i = 0; i < 4; ++i)
        tile[ty + 8 * i][tx] = s[(size_t)(k0 + ty + 8 * i) * N + n0 + tx];
    __syncthreads();
#pragma unroll
    for (int i = 0; i < 4; ++i)
        d[(size_t)(n0 + ty + 8 * i) * K + k0 + tx] = f2b(tile[tx][ty + 8 * i]);
}

__global__ void biaspack_kernel(const float* __restrict__ qb, const float* __restrict__ kb,
                                const float* __restrict__ vb, float* __restrict__ dst) {
    int i = blockIdx.x * 256 + threadIdx.x;   // 3072
    dst[i] = i < 1024 ? qb[i] : (i < 2048 ? kb[i - 1024] : vb[i - 2048]);
}

// ---------------------------------------------------------------------------
// Split-fp16 single-pass GEMM: C = (Ah+Al)@(Bh+Bl)^T + bias  (drops Al*Bl)
// ASYNC staging (proven round 13).
template<int EPI>
__global__ __launch_bounds__(256) void mmsplit_kernel(
    const _Float16* __restrict__ Ah, const _Float16* __restrict__ Al,
    const _Float16* __restrict__ Bh, const _Float16* __restrict__ Bl,
    const float* __restrict__ bias, float* __restrict__ C,
    _Float16* __restrict__ Ch, _Float16* __restrict__ Cl,
    int M, int N, int K)
{
    __shared__ char smem[65536];
    const int tid = threadIdx.x;
    const int lane = tid & 63, wave = tid >> 6;
    const int wm = wave >> 1, wn = wave & 1;
    const int bm = blockIdx.y * 128, bn = blockIdx.x * 128;
    const int l15 = lane & 15, l4 = lane >> 4;
    const int srow = tid >> 3;
    const int sc = tid & 7;

    f32x4 acc[4][4];
#pragma unroll
    for (int i = 0; i < 4; ++i)
#pragma unroll
        for (int j = 0; j < 4; ++j) acc[i][j] = 0.f;

    for (int k0 = 0; k0 < K; k0 += 64) {
#pragma unroll
        for (int p = 0; p < 4; ++p) {
            int row = p * 32 + srow;
            int gsw = (sc ^ (row & 7)) * 8;       // inverse-swizzled k offset
            size_t ga = (size_t)(bm + row) * K + k0 + gsw;
            size_t gb = (size_t)(bn + row) * K + k0 + gsw;
            int ldst = p * 4096 + tid * 16;       // linear: row*128 + sc*16
            async16(smem + ldst,         Ah + ga);
            async16(smem + 16384 + ldst, Al + ga);
            async16(smem + 32768 + ldst, Bh + gb);
            async16(smem + 49152 + ldst, Bl + gb);
        }
        __syncthreads();
#pragma unroll
        for (int kk = 0; kk < 2; ++kk) {
            f16x8 afh[4], afl[4], bfh[4], bfl[4];
            int g = kk * 4 + l4;
#pragma unroll
            for (int mi = 0; mi < 4; ++mi) {
                int row = wm * 64 + mi * 16 + l15;
                int o = row * 128 + ((g ^ (row & 7)) << 4);
                afh[mi] = *(const f16x8*)(smem + o);
                afl[mi] = *(const f16x8*)(smem + 16384 + o);
            }
#pragma unroll
            for (int ni = 0; ni < 4; ++ni) {
                int row = wn * 64 + ni * 16 + l15;
                int o = row * 128 + ((g ^ (row & 7)) << 4);
                bfh[ni] = *(const f16x8*)(smem + 32768 + o);
                bfl[ni] = *(const f16x8*)(smem + 49152 + o);
            }
#pragma unroll
            for (int mi = 0; mi < 4; ++mi)
#pragma unroll
                for (int ni = 0; ni < 4; ++ni) {
                    acc[mi][ni] = __builtin_amdgcn_mfma_f32_16x16x32_f16(
                        afh[mi], bfh[ni], acc[mi][ni], 0, 0, 0);
                    acc[mi][ni] = __builtin_amdgcn_mfma_f32_16x16x32_f16(
                        afh[mi], bfl[ni], acc[mi][ni], 0, 0, 0);
                    acc[mi][ni] = __builtin_amdgcn_mfma_f32_16x16x32_f16(
                        afl[mi], bfh[ni], acc[mi][ni], 0, 0, 0);
                }
        }
        __syncthreads();
    }
#pragma unroll
    for (int ni = 0; ni < 4; ++ni) {
        int col = bn + wn * 64 + ni * 16 + l15;
        float bv = bias[col];
#pragma unroll
        for (int mi = 0; mi < 4; ++mi)
#pragma unroll
            for (int rr = 0; rr < 4; ++rr) {
                int row = bm + wm * 64 + mi * 16 + l4 * 4 + rr;
                float v = acc[mi][ni][rr] + bv;
                size_t idx = (size_t)row * N + col;
                if (EPI == 0) {
                    C[idx] = v;
                } else {
                    v = fmaxf(v, 0.f);
                    _Float16 h = (_Float16)v;
                    Ch[idx] = h;
                    Cl[idx] = (_Float16)(v - (float)h);
                }
            }
    }
}

// ---------------------------------------------------------------------------
// Vocab GEMM: bf16 MFMA, 128x128, N-fastest grid (best write locality,
// 232us measured rounds 9/15), async staging, plain stores.
__global__ __launch_bounds__(256) void mmv_kernel(
    const bf16* __restrict__ A, const bf16* __restrict__ BT,
    const float* __restrict__ bias, float* __restrict__ C,
    int M, int N, int K)
{
    const int bm = blockIdx.y * 128;
    const int bn = blockIdx.x * 128;
    __shared__ char smem[32768];
    const int tid = threadIdx.x;
    const int lane = tid & 63, wave = tid >> 6;
    const int wm = wave >> 1, wn = wave & 1;
    const int l15 = lane & 15, l4 = lane >> 4;
    const int srow = tid >> 3;
    const int sc = tid & 7;

    f32x4 acc[4][4];
#pragma unroll
    for (int i = 0; i < 4; ++i)
#pragma unroll
        for (int j = 0; j < 4; ++j) acc[i][j] = 0.f;

    for (int k0 = 0; k0 < K; k0 += 64) {
#pragma unroll
        for (int p = 0; p < 4; ++p) {
            int row = p * 32 + srow;
            int gsw = (sc ^ (row & 7)) * 8;
            int ldst = p * 4096 + tid * 16;
            async16(smem + ldst,         A + (size_t)(bm + row) * K + k0 + gsw);
            async16(smem + 16384 + ldst, BT + (size_t)(bn + row) * K + k0 + gsw);
        }
        __syncthreads();
#pragma unroll
        for (int kk = 0; kk < 2; ++kk) {
            bf16x8 af[4], bfv[4];
            int g = kk * 4 + l4;
#pragma unroll
            for (int mi = 0; mi < 4; ++mi) {
                int row = wm * 64 + mi * 16 + l15;
                af[mi] = *(const bf16x8*)(smem + row * 128 + ((g ^ (row & 7)) << 4));
            }
#pragma unroll
            for (int ni = 0; ni < 4; ++ni) {
                int row = wn * 64 + ni * 16 + l15;
                bfv[ni] = *(const bf16x8*)(smem + 16384 + row * 128 + ((g ^ (row & 7)) << 4));
            }
#pragma unroll
            for (int mi = 0; mi < 4; ++mi)
#pragma unroll
                for (int ni = 0; ni < 4; ++ni)
                    acc[mi][ni] = __builtin_amdgcn_mfma_f32_16x16x32_bf16(
                        af[mi], bfv[ni], acc[mi][ni], 0, 0, 0);
        }
        __syncthreads();
    }
#pragma unroll
    for (int ni = 0; ni < 4; ++ni) {
        int col = bn + wn * 64 + ni * 16 + l15;
        float bv = bias[col];
#pragma unroll
        for (int mi = 0; mi < 4; ++mi)
#pragma unroll
            for (int rr = 0; rr < 4; ++rr) {
                int row = bm + wm * 64 + mi * 16 + l4 * 4 + rr;
                C[(size_t)row * N + col] = acc[mi][ni][rr] + bv;
            }
    }
}

// ---------------------------------------------------------------------------
// MoE routing
__global__ void route_kernel(const float* __restrict__ we,
                             int* __restrict__ cnt, int* __restrict__ lists) {
    int e = blockIdx.x;
    __shared__ int lcnt;
    if (threadIdx.x == 0) lcnt = 0;
    __syncthreads();
    for (int t = threadIdx.x; t < NT; t += 256) {
        if (we[t * 8 + e] != 0.f) {
            int pos = atomicAdd(&lcnt, 1);
            lists[e * NT + pos] = t;
        }
    }
    __syncthreads();
    if (threadIdx.x == 0) cnt[e] = lcnt;
}

// ---------------------------------------------------------------------------
// Batched gathered expert FFN-1 (async staging; writes expert-disjoint).
__global__ __launch_bounds__(256) void mmg1b_kernel(
    const bf16* __restrict__ A, const bf16* __restrict__ e1tall,
    const float* __restrict__ eb1, bf16* __restrict__ hcall,
    const int* __restrict__ lists, const int* __restrict__ cnt)
{
    const int e = blockIdx.y >> 4;
    const int m = min(cnt[e], ECAP);
    const int bm = (blockIdx.y & 15) * 128;
    if (bm >= m) return;
    const bf16* BT = e1tall + (size_t)e * NDFF * ND;
    const float* bias = eb1 + e * NDFF;
    bf16* Cc = hcall + (size_t)e * ECAP * NDFF;
    __shared__ char smem[32768];
    const int tid = threadIdx.x;
    const int lane = tid & 63, wave = tid >> 6;
    const int wm = wave >> 1, wn = wave & 1;
    const int bn = blockIdx.x * 128;
    const int l15 = lane & 15, l4 = lane >> 4;
    const int srow = tid >> 3;
    const int sc = tid & 7;
    const int* lst = lists + e * NT;
    const int K = 1024, N = NDFF;
    int trow[4];
#pragma unroll
    for (int p = 0; p < 4; ++p) {
        int gr = bm + p * 32 + srow;
        trow[p] = lst[gr < m ? gr : m - 1];
    }

    f32x4 acc[4][4];
#pragma unroll
    for (int i = 0; i < 4; ++i)
#pragma unroll
        for (int j = 0; j < 4; ++j) acc[i][j] = 0.f;

    for (int k0 = 0; k0 < K; k0 += 64) {
#pragma unroll
        for (int p = 0; p < 4; ++p) {
            int row = p * 32 + srow;
            int gsw = (sc ^ (row & 7)) * 8;
            int ldst = p * 4096 + tid * 16;
            async16(smem + ldst,         A + (size_t)trow[p] * K + k0 + gsw);
            async16(smem + 16384 + ldst, BT + (size_t)(bn + row) * K + k0 + gsw);
        }
        __syncthreads();
#pragma unroll
        for (int kk = 0; kk < 2; ++kk) {
            bf16x8 af[4], bfv[4];
            int g = kk * 4 + l4;
#pragma unroll
            for (int mi = 0; mi < 4; ++mi) {
                int row = wm * 64 + mi * 16 + l15;
                af[mi] = *(const bf16x8*)(smem + row * 128 + ((g ^ (row & 7)) << 4));
            }
#pragma unroll
            for (int ni = 0; ni < 4; ++ni) {
                int row = wn * 64 + ni * 16 + l15;
                bfv[ni] = *(const bf16x8*)(smem + 16384 + row * 128 + ((g ^ (row & 7)) << 4));
            }
#pragma unroll
            for (int mi = 0; mi < 4; ++mi)
#pragma unroll
                for (int ni = 0; ni < 4; ++ni)
                    acc[mi][ni] = __builtin_amdgcn_mfma_f32_16x16x32_bf16(
                        af[mi], bfv[ni], acc[mi][ni], 0, 0, 0);
        }
        __syncthreads();
    }
#pragma unroll
    for (int ni = 0; ni < 4; ++ni) {
        int col = bn + wn * 64 + ni * 16 + l15;
        float bv = bias[col];
#pragma unroll
        for (int mi = 0; mi < 4; ++mi)
#pragma unroll
            for (int rr = 0; rr < 4; ++rr) {
                int row = bm + wm * 64 + mi * 16 + l4 * 4 + rr;
                if (row < m)
                    Cc[(size_t)row * N + col] = f2b(fmaxf(acc[mi][ni][rr] + bv, 0.f));
            }
    }
}

// ---------------------------------------------------------------------------
// Batched expert FFN-2 + scatter (async staging; atomicAdd for the 2-expert
// overlap; two adds onto exact zero are order-independent bitwise).
__global__ __launch_bounds__(256) void mmg2b_kernel(
    const bf16* __restrict__ hcall, const bf16* __restrict__ e2tall,
    const float* __restrict__ eb2, float* __restrict__ macc,
    const float* __restrict__ we,
    const int* __restrict__ lists, const int* __restrict__ cnt)
{
    const int e = blockIdx.y >> 4;
    const int m = min(cnt[e], ECAP);
    const int bm = (blockIdx.y & 15) * 128;
    if (bm >= m) return;
    const bf16* Ac = hcall + (size_t)e * ECAP * NDFF;
    const bf16* BT = e2tall + (size_t)e * ND * NDFF;
    const float* bias = eb2 + e * ND;
    __shared__ char smem[32768];
    const int tid = threadIdx.x;
    const int lane = tid & 63, wave = tid >> 6;
    const int wm = wave >> 1, wn = wave & 1;
    const int bn = blockIdx.x * 128;
    const int l15 = lane & 15, l4 = lane >> 4;
    const int srow = tid >> 3;
    const int sc = tid & 7;
    const int* lst = lists + e * NT;
    const int K = NDFF, N = ND;

    f32x4 acc[4][4];
#pragma unroll
    for (int i = 0; i < 4; ++i)
#pragma unroll
        for (int j = 0; j < 4; ++j) acc[i][j] = 0.f;

    for (int k0 = 0; k0 < K; k0 += 64) {
#pragma unroll
        for (int p = 0; p < 4; ++p) {
            int row = p * 32 + srow;
            int ar = bm + row; ar = ar < m ? ar : m - 1;
            int gsw = (sc ^ (row & 7)) * 8;
            int ldst = p * 4096 + tid * 16;
            async16(smem + ldst,         Ac + (size_t)ar * K + k0 + gsw);
            async16(smem + 16384 + ldst, BT + (size_t)(bn + row) * K + k0 + gsw);
        }
        __syncthreads();
#pragma unroll
        for (int kk = 0; kk < 2; ++kk) {
            bf16x8 af[4], bfv[4];
            int g = kk * 4 + l4;
#pragma unroll
            for (int mi = 0; mi < 4; ++mi) {
                int row = wm * 64 + mi * 16 + l15;
                af[mi] = *(const bf16x8*)(smem + row * 128 + ((g ^ (row & 7)) << 4));
            }
#pragma unroll
            for (int ni = 0; ni < 4; ++ni) {
                int row = wn * 64 + ni * 16 + l15;
                bfv[ni] = *(const bf16x8*)(smem + 16384 + row * 128 + ((g ^ (row & 7)) << 4));
            }
#pragma unroll
            for (int mi = 0; mi < 4; ++mi)
#pragma unroll
                for (int ni = 0; ni < 4; ++ni)
                    acc[mi][ni] = __builtin_amdgcn_mfma_f32_16x16x32_bf16(
                        af[mi], bfv[ni], acc[mi][ni], 0, 0, 0);
        }
        __syncthreads();
    }
#pragma unroll
    for (int ni = 0; ni < 4; ++ni) {
        int col = bn + wn * 64 + ni * 16 + l15;
        float bv = bias[col];
#pragma unroll
        for (int mi = 0; mi < 4; ++mi)
#pragma unroll
            for (int rr = 0; rr < 4; ++rr) {
                int row = bm + wm * 64 + mi * 16 + l4 * 4 + rr;
                if (row < m) {
                    int t = lst[row];
                    atomicAdd(&macc[(size_t)t * N + col],
                              we[t * 8 + e] * (acc[mi][ni][rr] + bv));
                }
            }
    }
}

// ---------------------------------------------------------------------------
// RoPE + head-pack split (proven round 9)
__global__ __launch_bounds__(256) void ropehs_kernel(
    const float* __restrict__ qkv, const float* __restrict__ c, const float* __restrict__ sn,
    _Float16* __restrict__ Qh, _Float16* __restrict__ Ql,
    _Float16* __restrict__ Kh, _Float16* __restrict__ Kl,
    _Float16* __restrict__ VTh, _Float16* __restrict__ VTl)
{
    int st = blockIdx.x, bh = blockIdx.y;
    int b = bh >> 4, h = bh & 15;
    int s0 = st * 64;
    int tid = threadIdx.x;
#pragma unroll
    for (int it = 0; it < 8; ++it) {
        int idx = tid + 256 * it;       // 64 s x 32 j
        int sl = idx >> 5, j = idx & 31;
        int s = s0 + sl;
        size_t t = (size_t)b * NS + s;
        float cv = c[s * 32 + j], sv = sn[s * 32 + j];
        const float* base = qkv + t * 3072 + h * 64;
        float q1 = base[j], q2 = base[32 + j];
        float k1 = base[1024 + j], k2 = base[1024 + 32 + j];
        float qr1 = (q1 * cv - q2 * sv) * 0.125f;
        float qr2 = (q2 * cv + q1 * sv) * 0.125f;
        float kr1 = k1 * cv - k2 * sv;
        float kr2 = k2 * cv + k1 * sv;
        size_t o = (size_t)bh * 65536 + (size_t)s * 64;
        _Float16 hh1 = (_Float16)qr1, hh2 = (_Float16)qr2;
        Qh[o + j] = hh1;      Ql[o + j] = (_Float16)(qr1 - (float)hh1);
        Qh[o + 32 + j] = hh2; Ql[o + 32 + j] = (_Float16)(qr2 - (float)hh2);
        _Float16 kh1 = (_Float16)kr1, kh2 = (_Float16)kr2;
        Kh[o + j] = kh1;      Kl[o + j] = (_Float16)(kr1 - (float)kh1);
        Kh[o + 32 + j] = kh2; Kl[o + 32 + j] = (_Float16)(kr2 - (float)kh2);
    }
    __shared__ float vt[64][65];
    int dl = tid & 63, sq = tid >> 6;
#pragma unroll
    for (int i = 0; i < 16; ++i) {
        int sl = sq + 4 * i;
        size_t t = (size_t)b * NS + s0 + sl;
        vt[sl][dl] = qkv[t * 3072 + 2048 + h * 64 + dl];
    }
    __syncthreads();
#pragma unroll
    for (int i = 0; i < 16; ++i) {
        int d = sq + 4 * i;
        float v = vt[dl][d];
        _Float16 hv = (_Float16)v;
        size_t o = (size_t)bh * 65536 + (size_t)d * 1024 + s0 + dl;
        VTh[o] = hv;
        VTl[o] = (_Float16)(v - (float)hv);
    }
}

// ---------------------------------------------------------------------------
// Scores (proven round 9)
__global__ __launch_bounds__(256) void scores_kernel(
    const _Float16* __restrict__ Qh, const _Float16* __restrict__ Ql,
    const _Float16* __restrict__ Kh, const _Float16* __restrict__ Kl,
    float* __restrict__ S)
{
    int bh = blockIdx.z;
    int q0 = blockIdx.y * 128, k0 = blockIdx.x * 128;
    int lane = threadIdx.x & 63, wave = threadIdx.x >> 6;
    int wm = wave >> 1, wn = wave & 1;
    int l15 = lane & 15, l4 = lane >> 4;
    size_t hb_ = (size_t)bh * 65536;
    f32x4 acc[4][4];
#pragma unroll
    for (int i = 0; i < 4; ++i)
#pragma unroll
        for (int j = 0; j < 4; ++j) acc[i][j] = 0.f;
#pragma unroll
    for (int kk = 0; kk < 2; ++kk) {
        f16x8 ah[4], al[4], bh2[4], bl[4];
#pragma unroll
        for (int mi = 0; mi < 4; ++mi) {
            size_t o = hb_ + (size_t)(q0 + wm * 64 + mi * 16 + l15) * 64 + kk * 32 + l4 * 8;
            ah[mi] = *(const f16x8*)(Qh + o);
            al[mi] = *(const f16x8*)(Ql + o);
        }
#pragma unroll
        for (int ni = 0; ni < 4; ++ni) {
            size_t o = hb_ + (size_t)(k0 + wn * 64 + ni * 16 + l15) * 64 + kk * 32 + l4 * 8;
            bh2[ni] = *(const f16x8*)(Kh + o);
            bl[ni]  = *(const f16x8*)(Kl + o);
        }
#pragma unroll
        for (int mi = 0; mi < 4; ++mi)
#pragma unroll
            for (int ni = 0; ni < 4; ++ni) {
                acc[mi][ni] = __builtin_amdgcn_mfma_f32_16x16x32_f16(ah[mi], bh2[ni], acc[mi][ni], 0, 0, 0);
                acc[mi][ni] = __builtin_amdgcn_mfma_f32_16x16x32_f16(ah[mi], bl[ni],  acc[mi][ni], 0, 0, 0);
                acc[mi][ni] = __builtin_amdgcn_mfma_f32_16x16x32_f16(al[mi], bh2[ni], acc[mi][ni], 0, 0, 0);
            }
    }
    float* Sb = S + (size_t)bh * 1048576;
#pragma unroll
    for (int mi = 0; mi < 4; ++mi)
#pragma unroll
        for (int ni = 0; ni < 4; ++ni)
#pragma unroll
            for (int rr = 0; rr < 4; ++rr)
                Sb[(size_t)(q0 + wm * 64 + mi * 16 + l4 * 4 + rr) * 1024 + k0 + wn * 64 + ni * 16 + l15] =
                    acc[mi][ni][rr];
}

// ---------------------------------------------------------------------------
// Softmax -> packed fp16 hi|lo P (proven round 9)
__global__ __launch_bounds__(256) void softmaxp_kernel(float* __restrict__ S) {
    int row = blockIdx.x * 4 + (threadIdx.x >> 6);   // 32768 rows
    int lane = threadIdx.x & 63;
    float* Srow = S + (size_t)row * 1024;
    float f[16];
#pragma unroll
    for (int i = 0; i < 4; ++i) {
        float4 v = *(const float4*)(Srow + lane * 16 + i * 4);
        f[i * 4 + 0] = v.x; f[i * 4 + 1] = v.y; f[i * 4 + 2] = v.z; f[i * 4 + 3] = v.w;
    }
    float m = -1e30f;
#pragma unroll
    for (int j = 0; j < 16; ++j) m = fmaxf(m, f[j]);
#pragma unroll
    for (int off = 32; off; off >>= 1) m = fmaxf(m, __shfl_xor(m, off));
    float s = 0.f;
#pragma unroll
    for (int j = 0; j < 16; ++j) { f[j] = __expf(f[j] - m); s += f[j]; }
#pragma unroll
    for (int off = 32; off; off >>= 1) s += __shfl_xor(s, off);
    float inv = 1.f / s;
    f16x8 ph[2], pl[2];
#pragma unroll
    for (int j = 0; j < 16; ++j) {
        float p = f[j] * inv;
        _Float16 h = (_Float16)p;
        ph[j >> 3][j & 7] = h;
        pl[j >> 3][j & 7] = (_Float16)(p - (float)h);
    }
    _Float16* Pr = (_Float16*)Srow;
    *(f16x8*)(Pr + lane * 16) = ph[0];
    *(f16x8*)(Pr + lane * 16 + 8) = ph[1];
    *(f16x8*)(Pr + 1024 + lane * 16) = pl[0];
    *(f16x8*)(Pr + 1024 + lane * 16 + 8) = pl[1];
}

// ---------------------------------------------------------------------------
// PV (proven round 9)
__global__ __launch_bounds__(256) void pv_kernel(
    const float* __restrict__ Sp,
    const _Float16* __restrict__ VTh, const _Float16* __restrict__ VTl,
    _Float16* __restrict__ oh, _Float16* __restrict__ ol)
{
    int q0 = blockIdx.x * 64;
    int bh = blockIdx.y;
    int b = bh >> 4, h = bh & 15;
    int lane = threadIdx.x & 63, wave = threadIdx.x >> 6;
    int wm = wave >> 1, wn = wave & 1;
    int l15 = lane & 15, l4 = lane >> 4;
    const _Float16* Pb = (const _Float16*)(Sp + (size_t)bh * 1048576);
    size_t vb_ = (size_t)bh * 65536;
    f32x4 acc[2][2];
    acc[0][0] = 0.f; acc[0][1] = 0.f; acc[1][0] = 0.f; acc[1][1] = 0.f;
    for (int kv = 0; kv < 1024; kv += 32) {
        f16x8 ah[2], al[2], bh2[2], bl[2];
#pragma unroll
        for (int mi = 0; mi < 2; ++mi) {
            const _Float16* pr = Pb + (size_t)(q0 + wm * 32 + mi * 16 + l15) * 2048 + kv + l4 * 8;
            ah[mi] = *(const f16x8*)pr;
            al[mi] = *(const f16x8*)(pr + 1024);
        }
#pragma unroll
        for (int ni = 0; ni < 2; ++ni) {
            size_t o = vb_ + (size_t)(wn * 32 + ni * 16 + l15) * 1024 + kv + l4 * 8;
            bh2[ni] = *(const f16x8*)(VTh + o);
            bl[ni]  = *(const f16x8*)(VTl + o);
        }
#pragma unroll
        for (int mi = 0; mi < 2; ++mi)
#pragma unroll
            for (int ni = 0; ni < 2; ++ni) {
                acc[mi][ni] = __builtin_amdgcn_mfma_f32_16x16x32_f16(ah[mi], bh2[ni], acc[mi][ni], 0, 0, 0);
                acc[mi][ni] = __builtin_amdgcn_mfma_f32_16x16x32_f16(ah[mi], bl[ni],  acc[mi][ni], 0, 0, 0);
                acc[mi][ni] = __builtin_amdgcn_mfma_f32_16x16x32_f16(al[mi], bh2[ni], acc[mi][ni], 0, 0, 0);
            }
    }
#pragma unroll
    for (int mi = 0; mi < 2; ++mi)
#pragma unroll
        for (int ni = 0; ni < 2; ++ni)
#pragma unroll
            for (int rr = 0; rr < 4; ++rr) {
                int qrow = q0 + wm * 32 + mi * 16 + l4 * 4 + rr;
                int d = wn * 32 + ni * 16 + l15;
                size_t idx = ((size_t)(b * NS + qrow)) * ND + h * 64 + d;
                float v = acc[mi][ni][rr];
                _Float16 hv = (_Float16)v;
                oh[idx] = hv;
                ol[idx] = (_Float16)(v - (float)hv);
            }
}

// ---------------------------------------------------------------------------
// Residual + LayerNorm with fused outputs: fp32, fp16 hi/lo split, bf16.
__global__ __launch_bounds__(256) void ln_kernel(
    const float* __restrict__ res, const float* __restrict__ y,
    const float* __restrict__ g, const float* __restrict__ b,
    float* __restrict__ outf,
    _Float16* __restrict__ dh, _Float16* __restrict__ dl,
    bf16* __restrict__ outb)
{
    int t = blockIdx.x, tid = threadIdx.x;
    size_t base = (size_t)t * ND;
    float v[4];
    float s = 0.f, s2 = 0.f;
#pragma unroll
    for (int i = 0; i < 4; ++i) {
        int d = tid + 256 * i;
        float val = y[base + d];
        if (res) val += res[base + d];
        v[i] = val;
        s += val;
        s2 += val * val;
    }
    for (int off = 32; off; off >>= 1) {
        s  += __shfl_xor(s, off);
        s2 += __shfl_xor(s2, off);
    }
    __shared__ float rs[4], rs2[4];
    int wave = tid >> 6, lane = tid & 63;
    if (!lane) { rs[wave] = s; rs2[wave] = s2; }
    __syncthreads();
    s = rs[0] + rs[1] + rs[2] + rs[3];
    s2 = rs2[0] + rs2[1] + rs2[2] + rs2[3];
    float mu = s / ND;
    float var = s2 / ND - mu * mu;
    float rstd = rsqrtf(var + 1e-5f);
#pragma unroll
    for (int i = 0; i < 4; ++i) {
        int d = tid + 256 * i;
        float val = (v[i] - mu) * rstd * g[d] + b[d];
        if (outf) outf[base + d] = val;
        if (dh) {
            _Float16 h = (_Float16)val;
            dh[base + d] = h;
            dl[base + d] = (_Float16)(val - (float)h);
        }
        if (outb) outb[base + d] = f2b(val);
    }
}

// ---------------------------------------------------------------------------
__global__ __launch_bounds__(256) void gate_kernel(
    const float* __restrict__ x, const float* __restrict__ gw,
    const float* __restrict__ gb, float* __restrict__ we)
{
    int t = blockIdx.x, tid = threadIdx.x;
    float acc[8] = {};
#pragma unroll
    for (int i = 0; i < 4; ++i) {
        int d = tid * 4 + i;
        float xv = x[(size_t)t * ND + d];
#pragma unroll
        for (int e = 0; e < 8; ++e) acc[e] += xv * gw[d * 8 + e];
    }
    for (int off = 32; off; off >>= 1)
#pragma unroll
        for (int e = 0; e < 8; ++e) acc[e] += __shfl_xor(acc[e], off);
    __shared__ float red[4][8];
    int wave = tid >> 6, lane = tid & 63;
    if (!lane)
#pragma unroll
        for (int e = 0; e < 8; ++e) red[wave][e] = acc[e];
    __syncthreads();
    if (tid == 0) {
        float lg[8];
#pragma unroll
        for (int e = 0; e < 8; ++e)
            lg[e] = red[0][e] + red[1][e] + red[2][e] + red[3][e] + gb[e];
        int i1 = 0;
        for (int e = 1; e < 8; ++e) if (lg[e] > lg[i1]) i1 = e;
        int i2 = -1;
        for (int e = 0; e < 8; ++e) if (e != i1 && (i2 < 0 || lg[e] > lg[i2])) i2 = e;
        float e2 = __expf(lg[i2] - lg[i1]);
        float denom = 1.f + e2;
#pragma unroll
        for (int e = 0; e < 8; ++e) we[t * 8 + e] = 0.f;
        we[t * 8 + i1] = 1.f / denom;
        we[t * 8 + i2] = e2 / denom;
    }
}

__global__ void zero_kernel(float* __restrict__ p, int n) {
    int i = blockIdx.x * blockDim.x + threadIdx.x;
    if (i < n) p[i] = 0.f;
}

// ---------------------------------------------------------------------------
extern "C" void kernel_launch(void* const* d_in, const int* in_sizes, int n_in,
                              void* d_out, int out_size, void* d_ws, size_t ws_size,
                              hipStream_t stream) {
    (void)in_sizes; (void)n_in; (void)out_size; (void)ws_size;
    const int*   src  = (const int*)  d_in[0];
    const float* emb  = (const float*)d_in[1];
    const float* qw   = (const float*)d_in[2];
    const float* qb   = (const float*)d_in[3];
    const float* kw   = (const float*)d_in[4];
    const float* kb   = (const float*)d_in[5];
    const float* vw   = (const float*)d_in[6];
    const float* vb   = (const float*)d_in[7];
    const float* ow   = (const float*)d_in[8];
    const float* ob   = (const float*)d_in[9];
    const float* f1w  = (const float*)d_in[10];
    const float* f1b  = (const float*)d_in[11];
    const float* f2w  = (const float*)d_in[12];
    const float* f2b_ = (const float*)d_in[13];
    const float* ln1g = (const float*)d_in[14];
    const float* ln1b = (const float*)d_in[15];
    const float* ln2g = (const float*)d_in[16];
    const float* ln2b = (const float*)d_in[17];
    const float* gw   = (const float*)d_in[18];
    const float* gb   = (const float*)d_in[19];
    const float* ew1  = (const float*)d_in[20];
    const float* eb1  = (const float*)d_in[21];
    const float* ew2  = (const float*)d_in[22];
    const float* eb2  = (const float*)d_in[23];
    const float* flng = (const float*)d_in[24];
    const float* flnb = (const float*)d_in[25];
    const float* outw = (const float*)d_in[26];
    const float* outb = (const float*)d_in[27];
    float* out = (float*)d_out;

    char* w = (char*)d_ws;
    size_t off = 0;
    auto alloc = [&](size_t bytes) -> char* {
        size_t cur = (off + 255) & ~(size_t)255;
        off = cur + bytes;
        return w + cur;
    };

    float* xbuf   = (float*)alloc((size_t)NT * ND * 4);
    float* qkvbuf = (float*)alloc((size_t)NT * 3072 * 4);
    float* tbuf   = (float*)alloc((size_t)NT * ND * 4);
    float* macc   = (float*)alloc((size_t)NT * ND * 4);
    // ---- span reused post-gate as hcall (88MB, all dead after gate) ----
    _Float16* xh  = (_Float16*)alloc((size_t)NT * ND * 2);
    _Float16* xl  = (_Float16*)alloc((size_t)NT * ND * 2);
    _Float16* oh  = (_Float16*)alloc((size_t)NT * ND * 2);
    _Float16* ol  = (_Float16*)alloc((size_t)NT * ND * 2);
    _Float16* wqkvh = (_Float16*)alloc((size_t)3072 * ND * 2);
    _Float16* wqkvl = (_Float16*)alloc((size_t)3072 * ND * 2);
    _Float16* woh = (_Float16*)alloc((size_t)ND * ND * 2);
    _Float16* wol = (_Float16*)alloc((size_t)ND * ND * 2);
    _Float16* w1h = (_Float16*)alloc((size_t)ND * NDFF * 2);
    _Float16* w1l = (_Float16*)alloc((size_t)ND * NDFF * 2);
    _Float16* w2h = (_Float16*)alloc((size_t)ND * NDFF * 2);
    _Float16* w2l = (_Float16*)alloc((size_t)ND * NDFF * 2);
    _Float16* Qhh = (_Float16*)alloc((size_t)32 * NS * 64 * 2);
    _Float16* Qll = (_Float16*)alloc((size_t)32 * NS * 64 * 2);
    _Float16* Khh = (_Float16*)alloc((size_t)32 * NS * 64 * 2);
    _Float16* Kll = (_Float16*)alloc((size_t)32 * NS * 64 * 2);
    _Float16* VTh = (_Float16*)alloc((size_t)32 * 64 * NS * 2);
    _Float16* VTl = (_Float16*)alloc((size_t)32 * 64 * NS * 2);
    // --------------------------------------------------------------------
    float* webuf  = (float*)alloc((size_t)NT * NE * 4);
    float* cbuf   = (float*)alloc((size_t)NS * 32 * 4);
    float* snbuf  = (float*)alloc((size_t)NS * 32 * 4);
    float* qkvbias = (float*)alloc(3072 * 4);
    int*   ecnt   = (int*)alloc(NE * 4);
    int*   elists = (int*)alloc((size_t)NE * NT * 4);
    bf16*  xb     = (bf16*)alloc((size_t)NT * ND * 2);
    bf16*  lnout  = (bf16*)alloc((size_t)NT * ND * 2);
    bf16*  outwt  = (bf16*)alloc((size_t)NV * ND * 2);       // 62.5MB
    char*  Sbig   = alloc(134217728);                        // 128MB

    float* Sbuf = (float*)Sbig;                    // attention phase
    _Float16* hh = (_Float16*)(Sbig + 33554432);   // FFN [32,48MB)
    _Float16* hl = (_Float16*)(Sbig + 50331648);   // FFN [48,64MB)
    bf16* e1tall = (bf16*)Sbig;                    // post-gate [0,64MB)
    bf16* e2tall = (bf16*)(Sbig + 67108864);       // post-gate [64,128MB)
    bf16* hcall  = (bf16*)xh;                      // 8 x ECAP x 4096 bf16 = 80MB

    const int NX = NT * ND;
    yarn_kernel<<<(NS * 32) / 256, 256, 0, stream>>>(cbuf, snbuf);
    embed_kernel<<<NX / 256, 256, 0, stream>>>(src, emb, xbuf, xh, xl);

    for (int l = 0; l < NL; ++l) {
        wtconvh_kernel<<<dim3(32, 32), 256, 0, stream>>>(qw + (size_t)l * 1048576, wqkvh, wqkvl, 1024, 1024);
        wtconvh_kernel<<<dim3(32, 32), 256, 0, stream>>>(kw + (size_t)l * 1048576, wqkvh + 1048576, wqkvl + 1048576, 1024, 1024);
        wtconvh_kernel<<<dim3(32, 32), 256, 0, stream>>>(vw + (size_t)l * 1048576, wqkvh + 2097152, wqkvl + 2097152, 1024, 1024);
        wtconvh_kernel<<<dim3(32, 32), 256, 0, stream>>>(ow + (size_t)l * 1048576, woh, wol, 1024, 1024);
        wtconvh_kernel<<<dim3(128, 32), 256, 0, stream>>>(f1w + (size_t)l * 4194304, w1h, w1l, 1024, 4096);
        wtconvh_kernel<<<dim3(32, 128), 256, 0, stream>>>(f2w + (size_t)l * 4194304, w2h, w2l, 4096, 1024);
        biaspack_kernel<<<12, 256, 0, stream>>>(qb + l * 1024, kb + l * 1024, vb + l * 1024, qkvbias);

        mmsplit_kernel<0><<<dim3(24, 16), 256, 0, stream>>>(xh, xl, wqkvh, wqkvl, qkvbias, qkvbuf, nullptr, nullptr, NT, 3072, 1024);
        ropehs_kernel<<<dim3(16, 32), 256, 0, stream>>>(qkvbuf, cbuf, snbuf, Qhh, Qll, Khh, Kll, VTh, VTl);
        scores_kernel<<<dim3(8, 8, 32), 256, 0, stream>>>(Qhh, Qll, Khh, Kll, Sbuf);
        softmaxp_kernel<<<8192, 256, 0, stream>>>(Sbuf);
        pv_kernel<<<dim3(16, 32), 256, 0, stream>>>(Sbuf, VTh, VTl, oh, ol);
        mmsplit_kernel<0><<<dim3(8, 16), 256, 0, stream>>>(oh, ol, woh, wol, ob + l * 1024, tbuf, nullptr, nullptr, NT, 1024, 1024);
        ln_kernel<<<NT, 256, 0, stream>>>(xbuf, tbuf, ln1g + l * 1024, ln1b + l * 1024, xbuf, xh, xl, nullptr);
        mmsplit_kernel<1><<<dim3(32, 16), 256, 0, stream>>>(xh, xl, w1h, w1l, f1b + l * 4096, nullptr, hh, hl, NT, 4096, 1024);
        mmsplit_kernel<0><<<dim3(8, 16), 256, 0, stream>>>(hh, hl, w2h, w2l, f2b_ + l * 1024, tbuf, nullptr, nullptr, NT, 1024, 4096);
        if (l < NL - 1)
            ln_kernel<<<NT, 256, 0, stream>>>(xbuf, tbuf, ln2g + l * 1024, ln2b + l * 1024, xbuf, xh, xl, nullptr);
        else
            ln_kernel<<<NT, 256, 0, stream>>>(xbuf, tbuf, ln2g + l * 1024, ln2b + l * 1024, xbuf, nullptr, nullptr, xb);
    }

    // Gate on exact fp32 x; route tokens to experts
    gate_kernel<<<NT, 256, 0, stream>>>(xbuf, gw, gb, webuf);
    route_kernel<<<NE, 256, 0, stream>>>(webuf, ecnt, elists);

    // Post-gate: batched sparse expert GEMMs + vocab projection
    zero_kernel<<<NX / 256, 256, 0, stream>>>(macc, NX);
    wtconv_kernel<<<dim3(1000, 32), 256, 0, stream>>>(outw, outwt, 1024, 32000);
    wtconvb_kernel<<<dim3(128, 32, NE), 256, 0, stream>>>(ew1, e1tall, 1024, 4096);
    wtconvb_kernel<<<dim3(32, 128, NE), 256, 0, stream>>>(ew2, e2tall, 4096, 1024);
    mmg1b_kernel<<<dim3(32, 128), 256, 0, stream>>>(xb, e1tall, eb1, hcall, elists, ecnt);
    mmg2b_kernel<<<dim3(8, 128), 256, 0, stream>>>(hcall, e2tall, eb2, macc, webuf, elists, ecnt);
    ln_kernel<<<NT, 256, 0, stream>>>(nullptr, macc, flng, flnb, nullptr, nullptr, nullptr, lnout);
    mmv_kernel<<<dim3(250, 16), 256, 0, stream>>>(lnout, outwt, outb, out, NT, NV, 1024);
}